// Round 15
// baseline (244.880 us; speedup 1.0000x reference)
//
#include <hip/hip_runtime.h>
#include <math.h>

// rois [128, 256, 14, 14] fp32; BS=2, roinum=64, HID=128, C=256
constexpr int CIN  = 256;
constexpr int HID  = 128;
constexpr int P    = 196;   // 14*14
constexpr int PP   = 49;    // 7*7
constexpr int NQ   = 12544; // 64*196 per batch
constexpr int NKEY = 3136;  // 64*49  per batch
constexpr int NS   = 5;     // key splits: 490 blocks <= 512 (2/CU residency cap)

using f32x4 = __attribute__((ext_vector_type(4))) float;
using s16x8 = __attribute__((ext_vector_type(8))) short;
using s16x4 = __attribute__((ext_vector_type(4))) short;
using u32x2 = __attribute__((ext_vector_type(2))) unsigned int;

#define GLOBAL_AS(p) ((const void __attribute__((address_space(1)))*)(p))
#define LDS_AS(p)    ((void __attribute__((address_space(3)))*)(p))

__device__ __forceinline__ unsigned short f2bf(float x) {
    unsigned int u = __float_as_uint(x);
    u += 0x7FFFu + ((u >> 16) & 1u);
    return (unsigned short)(u >> 16);
}
__device__ __forceinline__ float bf2f(unsigned short s) {
    return __uint_as_float(((unsigned int)s) << 16);
}

// ============ fused Q/K/V MFMA GEMM — round-14 exact (prep folded in).
// Launched 3x THIS ROUND for TIMING: idempotent (q/kmat/vt_g/wreb fully
// overwritten from rois/weights). dur_us - 194.6 = 2x gemm duration.
__global__ __launch_bounds__(128) void gemm_fused_kernel(
    const float* __restrict__ rois,
    const float* __restrict__ wq, const float* __restrict__ wk,
    const float* __restrict__ wv, const float* __restrict__ wre,
    const float* __restrict__ bq, const float* __restrict__ bk, const float* __restrict__ bv,
    unsigned short* __restrict__ q, unsigned short* __restrict__ kmat,
    unsigned short* __restrict__ vt_g, unsigned short* __restrict__ wreb)
{
    const int bx = blockIdx.x;
    const int t = threadIdx.x;

    if (bx == 648) {   // wre -> wreb (32768 floats)
        #pragma unroll 4
        for (int i = 0; i < 64; ++i) {
            const int idx = i * 128 + t;
            const float4 v = ((const float4*)wre)[idx];
            s16x4 o;
            o[0] = (short)f2bf(v.x); o[1] = (short)f2bf(v.y);
            o[2] = (short)f2bf(v.z); o[3] = (short)f2bf(v.w);
            *(s16x4*)(wreb + idx * 4) = o;
        }
        return;
    }

    const int wid = t >> 6, lane = t & 63;
    const int quad = lane >> 4, c = lane & 15;

    __shared__ unsigned short xT[64 * 264];   // staging tile (33.8 KB)

    f32x4 acc[4][4];
    #pragma unroll
    for (int i = 0; i < 4; ++i)
        #pragma unroll
        for (int j = 0; j < 4; ++j) acc[i][j] = (f32x4)(0.f);

    const int n_base = wid * 64;
    const int swr = ((c >> 2) & 3) << 3;   // read-side swizzle = ((row>>2)&3)<<3

    if (bx < 392) {
        // ---- Q: stage x-tile from rois (fp32 -> bf16 transpose in LDS)
        const int m0 = bx * 64;
        {
            const int c_loc = t >> 2;    // 0..31
            const int pq4   = t & 3;
            const int sw    = pq4 << 3;  // = ((row>>2)&3)<<3 for rows below
            #pragma unroll
            for (int ci = 0; ci < 8; ++ci) {
                const int ch = ci * 32 + c_loc;
                #pragma unroll
                for (int j = 0; j < 4; ++j) {
                    const int idx4 = (m0 >> 2) + pq4 + 4 * j;
                    const int n_img = idx4 / 49;
                    const int p4 = idx4 - n_img * 49;
                    const float4 v = ((const float4*)(rois + ((size_t)(n_img * CIN + ch)) * P))[p4];
                    const int r0 = (pq4 + 4 * j) * 4;
                    const int cs = ch ^ sw;
                    xT[(r0 + 0) * 264 + cs] = f2bf(v.x);
                    xT[(r0 + 1) * 264 + cs] = f2bf(v.y);
                    xT[(r0 + 2) * 264 + cs] = f2bf(v.z);
                    xT[(r0 + 3) * 264 + cs] = f2bf(v.w);
                }
            }
        }
        __syncthreads();

        // swapped: A = wq (rows n), B = x (rows m) -> C col=c->m, row=quad*4+rr->n
        #pragma unroll
        for (int ks = 0; ks < 8; ++ks) {
            s16x8 af[4], bf[4];
            #pragma unroll
            for (int mt = 0; mt < 4; ++mt)
                af[mt] = *(const s16x8*)&xT[(mt * 16 + c) * 264 + ((ks * 32 + quad * 8) ^ swr)];
            #pragma unroll
            for (int nt = 0; nt < 4; ++nt) {
                const float* wp = wq + (size_t)(n_base + nt * 16 + c) * CIN + ks * 32 + quad * 8;
                const float4 w0 = *(const float4*)wp;
                const float4 w1 = *(const float4*)(wp + 4);
                s16x8 bv8;
                bv8[0] = (short)f2bf(w0.x); bv8[1] = (short)f2bf(w0.y);
                bv8[2] = (short)f2bf(w0.z); bv8[3] = (short)f2bf(w0.w);
                bv8[4] = (short)f2bf(w1.x); bv8[5] = (short)f2bf(w1.y);
                bv8[6] = (short)f2bf(w1.z); bv8[7] = (short)f2bf(w1.w);
                bf[nt] = bv8;
            }
            #pragma unroll
            for (int mt = 0; mt < 4; ++mt)
                #pragma unroll
                for (int nt = 0; nt < 4; ++nt)
                    acc[mt][nt] = __builtin_amdgcn_mfma_f32_16x16x32_bf16(bf[nt], af[mt], acc[mt][nt], 0, 0, 0);
        }
        #pragma unroll
        for (int mt = 0; mt < 4; ++mt) {
            const int m = m0 + mt * 16 + c;
            #pragma unroll
            for (int nt = 0; nt < 4; ++nt) {
                const int n0 = n_base + nt * 16 + quad * 4;
                const float4 b4 = *(const float4*)&bq[n0];
                s16x4 o4;
                o4[0] = (short)f2bf(acc[mt][nt][0] + b4.x);
                o4[1] = (short)f2bf(acc[mt][nt][1] + b4.y);
                o4[2] = (short)f2bf(acc[mt][nt][2] + b4.z);
                o4[3] = (short)f2bf(acc[mt][nt][3] + b4.w);
                *(s16x4*)(q + (size_t)m * HID + n0) = o4;
            }
        }
        return;
    }

    // ---- K/V: one ROI per block — inline 2x2 maxpool from rois into xT.
    const int mode = (bx < 520) ? 1 : 2;
    const int n_roi = bx - ((mode == 1) ? 392 : 520);    // 0..127
    const int b = n_roi >> 6, r = n_roi & 63;
    {
        // units: (ch 0..255) x (py slot 0..7, guard py<7) = 2048 / 128 thr = 16
        #pragma unroll
        for (int i = 0; i < 16; ++i) {
            const int unit = i * 128 + t;
            const int ch = unit >> 3, py = unit & 7;
            if (py < 7) {
                const float* ra = rois + ((size_t)n_roi * CIN + ch) * P + py * 28;
                #pragma unroll
                for (int px = 0; px < 7; ++px) {
                    const float2 a = *(const float2*)(ra + px * 2);
                    const float2 bb = *(const float2*)(ra + 14 + px * 2);
                    const float m = fmaxf(fmaxf(a.x, a.y), fmaxf(bb.x, bb.y));
                    const int pp = py * 7 + px;
                    xT[pp * 264 + (ch ^ (((pp >> 2) & 3) << 3))] = f2bf(m);
                }
            }
        }
    }
    __syncthreads();

    if (mode == 1) {
        // K swapped: A = wk (rows n), B = pooled x (rows key) -> C col=c->key
        #pragma unroll
        for (int ks = 0; ks < 8; ++ks) {
            s16x8 af[4], bf[4];
            #pragma unroll
            for (int mt = 0; mt < 4; ++mt)
                af[mt] = *(const s16x8*)&xT[(mt * 16 + c) * 264 + ((ks * 32 + quad * 8) ^ swr)];
            #pragma unroll
            for (int nt = 0; nt < 4; ++nt) {
                const float* wp = wk + (size_t)(n_base + nt * 16 + c) * CIN + ks * 32 + quad * 8;
                const float4 w0 = *(const float4*)wp;
                const float4 w1 = *(const float4*)(wp + 4);
                s16x8 bv8;
                bv8[0] = (short)f2bf(w0.x); bv8[1] = (short)f2bf(w0.y);
                bv8[2] = (short)f2bf(w0.z); bv8[3] = (short)f2bf(w0.w);
                bv8[4] = (short)f2bf(w1.x); bv8[5] = (short)f2bf(w1.y);
                bv8[6] = (short)f2bf(w1.z); bv8[7] = (short)f2bf(w1.w);
                bf[nt] = bv8;
            }
            #pragma unroll
            for (int mt = 0; mt < 4; ++mt)
                #pragma unroll
                for (int nt = 0; nt < 4; ++nt)
                    acc[mt][nt] = __builtin_amdgcn_mfma_f32_16x16x32_bf16(bf[nt], af[mt], acc[mt][nt], 0, 0, 0);
        }
        // store keys m < 49 only (rows 49-63 of xT are stale garbage).
        #pragma unroll
        for (int mt = 0; mt < 4; ++mt) {
            const int m = mt * 16 + c;
            if (mt < 3 || c == 0) {   // m <= 48
                const size_t krow = (size_t)(b * NKEY + r * 49 + m) * HID;
                #pragma unroll
                for (int nt = 0; nt < 4; ++nt) {
                    const int n0 = n_base + nt * 16 + quad * 4;
                    const float4 b4 = *(const float4*)&bk[n0];
                    s16x4 o4;
                    o4[0] = (short)f2bf(acc[mt][nt][0] + b4.x);
                    o4[1] = (short)f2bf(acc[mt][nt][1] + b4.y);
                    o4[2] = (short)f2bf(acc[mt][nt][2] + b4.z);
                    o4[3] = (short)f2bf(acc[mt][nt][3] + b4.w);
                    *(s16x4*)(kmat + krow + n0) = o4;
                }
            }
        }
    } else {
        // V natural: A = pooled x (rows key), B = wv (rows d) -> row=quad*4+rr->key
        #pragma unroll
        for (int ks = 0; ks < 8; ++ks) {
            s16x8 af[4], bf[4];
            #pragma unroll
            for (int mt = 0; mt < 4; ++mt)
                af[mt] = *(const s16x8*)&xT[(mt * 16 + c) * 264 + ((ks * 32 + quad * 8) ^ swr)];
            #pragma unroll
            for (int nt = 0; nt < 4; ++nt) {
                const float* wp = wv + (size_t)(n_base + nt * 16 + c) * CIN + ks * 32 + quad * 8;
                const float4 w0 = *(const float4*)wp;
                const float4 w1 = *(const float4*)(wp + 4);
                s16x8 bv8;
                bv8[0] = (short)f2bf(w0.x); bv8[1] = (short)f2bf(w0.y);
                bv8[2] = (short)f2bf(w0.z); bv8[3] = (short)f2bf(w0.w);
                bv8[4] = (short)f2bf(w1.x); bv8[5] = (short)f2bf(w1.y);
                bv8[6] = (short)f2bf(w1.z); bv8[7] = (short)f2bf(w1.w);
                bf[nt] = bv8;
            }
            #pragma unroll
            for (int mt = 0; mt < 4; ++mt)
                #pragma unroll
                for (int nt = 0; nt < 4; ++nt)
                    acc[mt][nt] = __builtin_amdgcn_mfma_f32_16x16x32_bf16(af[mt], bf[nt], acc[mt][nt], 0, 0, 0);
        }
        // SCALAR stores: vrow + key0 can be odd (r*49) -> only 2B alignment.
        #pragma unroll
        for (int nt = 0; nt < 4; ++nt) {
            const int d = n_base + nt * 16 + c;
            const float bv_ = bv[d];
            const size_t vrow = ((size_t)b * HID + d) * NKEY + r * 49;
            #pragma unroll
            for (int mt = 0; mt < 4; ++mt) {
                const int key0 = mt * 16 + quad * 4;
                if (mt < 3) {          // keys key0..key0+3 <= 47
                    #pragma unroll
                    for (int rr = 0; rr < 4; ++rr)
                        vt_g[vrow + key0 + rr] = f2bf(acc[mt][nt][rr] + bv_);
                } else if (quad == 0) { // key0 = 48: only rr=0 valid
                    vt_g[vrow + 48] = f2bf(acc[mt][nt][0] + bv_);
                }
            }
        }
    }
}

// ============ MFMA attention (FROZEN, round-8 structure + XCD remap).
__global__ __launch_bounds__(256, 2) void attn_kernel(
    const unsigned short* __restrict__ q, const unsigned short* __restrict__ kmat,
    const unsigned short* __restrict__ vt_g,
    unsigned short* __restrict__ opart, float* __restrict__ lpart)
{
    // ---- bijective XCD remap (m204): 490 blocks, 8 XCDs, q=61 r=2.
    const int fid  = blockIdx.x;
    const int xcd  = fid & 7, slot = fid >> 3;
    const int wg   = (xcd < 2 ? xcd * 62 : 124 + (xcd - 2) * 61) + slot;
    const int g    = wg / NS;          // q-group 0..97
    const int s    = wg - g * NS;      // split 0..4 (consecutive within XCD)
    const int qblk = g % 49;
    const int b    = g / 49;

    const int tid  = threadIdx.x;
    const int w    = tid >> 6;
    const int lane = tid & 63;
    const int quad = lane >> 4;
    const int c    = lane & 15;
    const int qb   = qblk * 256 + w * 64;

    __shared__ unsigned short Kst[2][32 * 128];   // [buf][key][d], row 256B, XOR-swz (16KB)
    __shared__ unsigned short Vst[2][128 * 32];   // [buf][d][key], row 64B, slot-XOR (16KB)
    __shared__ unsigned short Ps[4][64 * 72];     // wave-private P round-trip (36.9KB)

    const unsigned short* qg = q    + (size_t)b * NQ   * HID;
    const unsigned short* kg = kmat + (size_t)b * NKEY * HID;
    const unsigned short* vt = vt_g + (size_t)b * HID  * NKEY;

    int koff[2], voff[2];
    #pragma unroll
    for (int i = 0; i < 2; ++i) {
        const int dstk = w * 2048 + (i * 64 + lane) * 16;
        koff[i] = dstk ^ (((dstk >> 8) & 7) << 4);
        const int chunk = i * 64 + lane;
        const int d = w * 32 + (chunk >> 2), sl = chunk & 3;
        voff[i] = d * (NKEY * 2) + ((sl ^ (d & 3)) * 16);
    }
    const char* kc = (const char*)kg;
    const char* vc = (const char*)vt;

    // 98 key-tiles split NS=5 ways: {20,20,20,19,19}
    const int B6[6] = {0, 20, 40, 60, 79, 98};
    const int kt0 = B6[s], kt1 = B6[s + 1];

    // ---- prologue: stage first tile; load Q frags (overlaps)
    {
        const char* ks_ = kc + (size_t)kt0 * 8192;
        const char* vs_ = vc + (size_t)kt0 * 64;
        #pragma unroll
        for (int i = 0; i < 2; ++i) {
            __builtin_amdgcn_global_load_lds(GLOBAL_AS(ks_ + koff[i]),
                LDS_AS((char*)&Kst[0][0] + w * 2048 + i * 1024), 16, 0, 0);
            __builtin_amdgcn_global_load_lds(GLOBAL_AS(vs_ + voff[i]),
                LDS_AS((char*)&Vst[0][0] + w * 2048 + i * 1024), 16, 0, 0);
        }
    }

    s16x8 qf[4][4];
    #pragma unroll
    for (int nt = 0; nt < 4; ++nt)
        #pragma unroll
        for (int ks = 0; ks < 4; ++ks)
            qf[nt][ks] = *(const s16x8*)(qg + (size_t)(qb + nt * 16 + c) * HID + ks * 32 + quad * 8);

    f32x4 Ob[4][8];
    #pragma unroll
    for (int nt = 0; nt < 4; ++nt)
        #pragma unroll
        for (int nd = 0; nd < 8; ++nd) Ob[nt][nd] = (f32x4)(0.f);
    float l[4] = {0.f, 0.f, 0.f, 0.f};

    __syncthreads();    // drains vmcnt: tile kt0 staged

    int buf = 0;
    for (int kt = kt0; kt < kt1; ++kt) {
        if (kt + 1 < kt1) {
            const char* ks_ = kc + (size_t)(kt + 1) * 8192;
            const char* vs_ = vc + (size_t)(kt + 1) * 64;
            #pragma unroll
            for (int i = 0; i < 2; ++i) {
                __builtin_amdgcn_global_load_lds(GLOBAL_AS(ks_ + koff[i]),
                    LDS_AS((char*)&Kst[buf ^ 1][0] + w * 2048 + i * 1024), 16, 0, 0);
                __builtin_amdgcn_global_load_lds(GLOBAL_AS(vs_ + voff[i]),
                    LDS_AS((char*)&Vst[buf ^ 1][0] + w * 2048 + i * 1024), 16, 0, 0);
            }
        }

        const char* Kb = (const char*)&Kst[buf][0];
        const char* Vb = (const char*)&Vst[buf][0];

        // ---- S^T = K.Q^T : K frags from LDS (swizzled read)
        f32x4 st[2][4];
        #pragma unroll
        for (int mt = 0; mt < 2; ++mt)
            #pragma unroll
            for (int nt = 0; nt < 4; ++nt) st[mt][nt] = (f32x4)(0.f);
        #pragma unroll
        for (int mt = 0; mt < 2; ++mt) {
            const int row = mt * 16 + c;
            s16x8 kf[4];
            #pragma unroll
            for (int ks = 0; ks < 4; ++ks)
                kf[ks] = *(const s16x8*)(Kb + ((row * 256 + ks * 64 + quad * 16) ^ ((c & 7) << 4)));
            #pragma unroll
            for (int ks = 0; ks < 4; ++ks)
                #pragma unroll
                for (int nt = 0; nt < 4; ++nt)
                    st[mt][nt] = __builtin_amdgcn_mfma_f32_16x16x32_bf16(kf[ks], qf[nt][ks], st[mt][nt], 0, 0, 0);
        }

        // ---- exp (no max: scores bounded, fp32-safe), pack -> Ps[q][key]
        #pragma unroll
        for (int mt = 0; mt < 2; ++mt) {
            #pragma unroll
            for (int nt = 0; nt < 4; ++nt) {
                const float e0 = __expf(st[mt][nt][0]);
                const float e1 = __expf(st[mt][nt][1]);
                const float e2 = __expf(st[mt][nt][2]);
                const float e3 = __expf(st[mt][nt][3]);
                l[nt] += (e0 + e1) + (e2 + e3);
                u32x2 pk;
                pk[0] = (unsigned int)f2bf(e0) | ((unsigned int)f2bf(e1) << 16);
                pk[1] = (unsigned int)f2bf(e2) | ((unsigned int)f2bf(e3) << 16);
                *(u32x2*)&Ps[w][(nt * 16 + c) * 72 + mt * 16 + quad * 4] = pk;
            }
        }
        // wave-private P: intra-wave DS ordering suffices.

        // ---- O += P.V : A=P from LDS, B=Vt from LDS (slot-XOR read)
        s16x8 pf[4];
        #pragma unroll
        for (int nt = 0; nt < 4; ++nt)
            pf[nt] = *(const s16x8*)&Ps[w][(nt * 16 + c) * 72 + quad * 8];
        #pragma unroll
        for (int g2 = 0; g2 < 2; ++g2) {
            s16x8 vf[4];
            #pragma unroll
            for (int dd = 0; dd < 4; ++dd) {
                const int d = (g2 * 4 + dd) * 16 + c;
                vf[dd] = *(const s16x8*)(Vb + (d * 64 + ((quad ^ (d & 3)) * 16)));
            }
            #pragma unroll
            for (int dd = 0; dd < 4; ++dd)
                #pragma unroll
                for (int nt = 0; nt < 4; ++nt)
                    Ob[nt][g2 * 4 + dd] = __builtin_amdgcn_mfma_f32_16x16x32_bf16(pf[nt], vf[dd], Ob[nt][g2 * 4 + dd], 0, 0, 0);
        }

        if (kt + 1 < kt1) __syncthreads();
        buf ^= 1;
    }

    // epilogue: bf16 unnormalized partials
    unsigned short* Op = opart + (size_t)(s * 2 + b) * NQ * HID;
    #pragma unroll
    for (int nt = 0; nt < 4; ++nt) {
        #pragma unroll
        for (int nd = 0; nd < 8; ++nd) {
            #pragma unroll
            for (int rr = 0; rr < 4; ++rr) {
                const int qrow = qb + nt * 16 + quad * 4 + rr;
                Op[(size_t)qrow * HID + nd * 16 + c] = f2bf(Ob[nt][nd][rr]);
            }
        }
    }
    #pragma unroll
    for (int nt = 0; nt < 4; ++nt) {
        l[nt] += __shfl_xor(l[nt], 16, 64);
        l[nt] += __shfl_xor(l[nt], 32, 64);
    }
    if (quad == 0) {
        float* lp = lpart + (size_t)(s * 2 + b) * NQ;
        #pragma unroll
        for (int nt = 0; nt < 4; ++nt) lp[qb + nt * 16 + c] = l[nt];
    }
}

// ============ outproj (round-11 exact, byte-frozen).
__global__ __launch_bounds__(256) void outproj_kernel(
    const float* __restrict__ rois,
    const unsigned short* __restrict__ opart, const float* __restrict__ lpart,
    const unsigned short* __restrict__ wreb, const float* __restrict__ bre,
    float* __restrict__ out)
{
    const int t = threadIdx.x;
    const int wid = t >> 6, lane = t & 63;
    const int quad = lane >> 4, c = lane & 15;
    const int m0 = blockIdx.x * 64;                 // global m in [0, 25088)
    const int b  = (m0 >= NQ) ? 1 : 0;

    __shared__ unsigned short ys[64 * 136];         // merged y tile bf16 [m][k]

    {
        const int m_loc = t >> 2, kq = t & 3;
        const int q_local = (m0 + m_loc) - b * NQ;
        float lsum = 0.f;
        #pragma unroll
        for (int sl = 0; sl < NS; ++sl)
            lsum += lpart[(size_t)(sl * 2 + b) * NQ + q_local];
        const float invl = 1.0f / lsum;
        #pragma unroll
        for (int ch = 0; ch < 4; ++ch) {
            float a8[8] = {0, 0, 0, 0, 0, 0, 0, 0};
            #pragma unroll
            for (int sl = 0; sl < NS; ++sl) {
                const s16x8 v = *(const s16x8*)&opart[
                    ((size_t)(sl * 2 + b) * NQ + q_local) * HID + kq * 32 + ch * 8];
                #pragma unroll
                for (int e = 0; e < 8; ++e) a8[e] += bf2f((unsigned short)v[e]);
            }
            s16x8 o;
            #pragma unroll
            for (int e = 0; e < 8; ++e) o[e] = (short)f2bf(a8[e] * invl);
            *(s16x8*)&ys[m_loc * 136 + kq * 32 + ch * 8] = o;
        }
    }
    __syncthreads();

    // wre frags: B-operand rows = o (this wave's 64 outputs)
    const int o_base = wid * 64;
    s16x8 wf[4][4];
    #pragma unroll
    for (int ot = 0; ot < 4; ++ot)
        #pragma unroll
        for (int ks = 0; ks < 4; ++ks)
            wf[ot][ks] = *(const s16x8*)(wreb + (size_t)(o_base + ot * 16 + c) * HID + ks * 32 + quad * 8);

    f32x4 acc[4][4];   // [mt][ot]: row=m (quad*4+rr), col=o (c)
    #pragma unroll
    for (int i = 0; i < 4; ++i)
        #pragma unroll
        for (int j = 0; j < 4; ++j) acc[i][j] = (f32x4)(0.f);

    #pragma unroll
    for (int ks = 0; ks < 4; ++ks) {
        s16x8 yf[4];
        #pragma unroll
        for (int mt = 0; mt < 4; ++mt)
            yf[mt] = *(const s16x8*)&ys[(mt * 16 + c) * 136 + ks * 32 + quad * 8];
        #pragma unroll
        for (int mt = 0; mt < 4; ++mt)
            #pragma unroll
            for (int ot = 0; ot < 4; ++ot)
                acc[mt][ot] = __builtin_amdgcn_mfma_f32_16x16x32_bf16(yf[mt], wf[ot][ks], acc[mt][ot], 0, 0, 0);
    }

    // ---- epilogue: out[n][o][p..p+3] = rois + bre[o] + T — float4 per (mt,ot)
    #pragma unroll
    for (int ot = 0; ot < 4; ++ot) {
        const int o = o_base + ot * 16 + c;
        const float br = bre[o];
        #pragma unroll
        for (int mt = 0; mt < 4; ++mt) {
            const int m_g = m0 + mt * 16 + quad * 4;     // +rr consecutive (p-contig)
            const int mm  = m_g - b * NQ;
            const int r_roi = mm / 196;
            const int p     = mm - r_roi * 196;
            const int n_img = b * 64 + r_roi;
            const size_t base = ((size_t)n_img * CIN + o) * P + p;
            const float4 rv = *(const float4*)&rois[base];
            float4 ov;
            ov.x = rv.x + br + acc[mt][ot][0];
            ov.y = rv.y + br + acc[mt][ot][1];
            ov.z = rv.z + br + acc[mt][ot][2];
            ov.w = rv.w + br + acc[mt][ot][3];
            *(float4*)&out[base] = ov;
        }
    }
}

extern "C" void kernel_launch(void* const* d_in, const int* in_sizes, int n_in,
                              void* d_out, int out_size, void* d_ws, size_t ws_size,
                              hipStream_t stream)
{
    (void)in_sizes; (void)n_in; (void)out_size; (void)ws_size;
    const float* rois = (const float*)d_in[0];
    const float* wq  = (const float*)d_in[2];
    const float* bq  = (const float*)d_in[3];
    const float* wk  = (const float*)d_in[4];
    const float* bk  = (const float*)d_in[5];
    const float* wv  = (const float*)d_in[6];
    const float* bv  = (const float*)d_in[7];
    const float* wre = (const float*)d_in[8];
    const float* bre = (const float*)d_in[9];
    float* out = (float*)d_out;

    char* ws = (char*)d_ws;
    // opart: 10 slices (NS=5 x 2) x NQ x HID bf16 = 32,112,640 B at 0.
    unsigned short* opart = (unsigned short*)(ws);
    unsigned short* q     = (unsigned short*)(ws + 32112640);   // 6,422,528
    unsigned short* kmat  = (unsigned short*)(ws + 38535168);   // 1,605,632
    unsigned short* vt_g  = (unsigned short*)(ws + 40140800);   // 1,605,632
    float*          lpart = (float*)         (ws + 41746432);   //   501,760
    unsigned short* wreb  = (unsigned short*)(ws + 42248192);   //    65,536
    // total: 42,313,728 B

    // INSTRUMENTATION: gemm launched 3x (idempotent). dur_us - 194.6 = 2x gemm.
    gemm_fused_kernel<<<dim3(649), 128, 0, stream>>>(rois, wq, wk, wv, wre,
                                                     bq, bk, bv, q, kmat, vt_g, wreb);
    gemm_fused_kernel<<<dim3(649), 128, 0, stream>>>(rois, wq, wk, wv, wre,
                                                     bq, bk, bv, q, kmat, vt_g, wreb);
    gemm_fused_kernel<<<dim3(649), 128, 0, stream>>>(rois, wq, wk, wv, wre,
                                                     bq, bk, bv, q, kmat, vt_g, wreb);
    attn_kernel<<<dim3(490), 256, 0, stream>>>(q, kmat, vt_g, opart, lpart);
    outproj_kernel<<<dim3(392), 256, 0, stream>>>(rois, opart, lpart, wreb, bre, out);
}

// Round 16
// 189.935 us; speedup vs baseline: 1.2893x; 1.2893x over previous
//
#include <hip/hip_runtime.h>
#include <math.h>

// rois [128, 256, 14, 14] fp32; BS=2, roinum=64, HID=128, C=256
constexpr int CIN  = 256;
constexpr int HID  = 128;
constexpr int P    = 196;   // 14*14
constexpr int PP   = 49;    // 7*7
constexpr int NQ   = 12544; // 64*196 per batch
constexpr int NKEY = 3136;  // 64*49  per batch
constexpr int NS   = 5;     // key splits: 490 blocks <= 512 (2/CU residency cap)

using f32x4 = __attribute__((ext_vector_type(4))) float;
using s16x8 = __attribute__((ext_vector_type(8))) short;
using s16x4 = __attribute__((ext_vector_type(4))) short;
using u32x2 = __attribute__((ext_vector_type(2))) unsigned int;

#define GLOBAL_AS(p) ((const void __attribute__((address_space(1)))*)(p))
#define LDS_AS(p)    ((void __attribute__((address_space(3)))*)(p))

__device__ __forceinline__ unsigned short f2bf(float x) {
    unsigned int u = __float_as_uint(x);
    u += 0x7FFFu + ((u >> 16) & 1u);
    return (unsigned short)(u >> 16);
}
__device__ __forceinline__ float bf2f(unsigned short s) {
    return __uint_as_float(((unsigned int)s) << 16);
}

// ============ prep (slim): maxpool -> xkv; weights -> bf16. xq removed —
// gemm Q-blocks stage straight from rois.
__global__ __launch_bounds__(256) void prep_kernel(
    const float* __restrict__ rois,
    const float* __restrict__ wq, const float* __restrict__ wk,
    const float* __restrict__ wv, const float* __restrict__ wre,
    unsigned short* __restrict__ xkv,
    unsigned short* __restrict__ wqb, unsigned short* __restrict__ wkb,
    unsigned short* __restrict__ wvb, unsigned short* __restrict__ wreb)
{
    const int bx = blockIdx.x;
    const int t  = threadIdx.x;

    if (bx >= 512) {
        const int which = bx - 512;
        const float* src = (which == 0) ? wq : (which == 1) ? wk : (which == 2) ? wv : wre;
        unsigned short* dst = (which == 0) ? wqb : (which == 1) ? wkb
                             : (which == 2) ? wvb : wreb;
        #pragma unroll 4
        for (int i = 0; i < 32; ++i) {
            const int idx = i * 256 + t;
            const float4 v = ((const float4*)src)[idx];
            s16x4 o;
            o[0] = (short)f2bf(v.x); o[1] = (short)f2bf(v.y);
            o[2] = (short)f2bf(v.z); o[3] = (short)f2bf(v.w);
            *(s16x4*)(dst + idx * 4) = o;
        }
        return;
    }

    const int n = bx >> 2;      // ROI index 0..127
    const int g = bx & 3;       // channel group (64 ch)
    const int b = n >> 6, r = n & 63;
    __shared__ float xT[196 * 68];   // [px][ch] fp32, pitch 68 (53 KB)

    const int c_loc = t >> 2;   // 0..63
    const int pq    = t & 3;

    const float4* row4 = (const float4*)(rois + ((size_t)n * CIN + g * 64 + c_loc) * P);
    #pragma unroll
    for (int j = 0; j < 13; ++j) {
        const int idx4 = pq + 4 * j;
        if (idx4 < 49) {
            const float4 v = row4[idx4];
            xT[(idx4 * 4 + 0) * 68 + c_loc] = v.x;
            xT[(idx4 * 4 + 1) * 68 + c_loc] = v.y;
            xT[(idx4 * 4 + 2) * 68 + c_loc] = v.z;
            xT[(idx4 * 4 + 3) * 68 + c_loc] = v.w;
        }
    }
    __syncthreads();

    // maxpool 2x2 -> xkv: 49 pp x 64 ch
    #pragma unroll
    for (int i = 0; i < 2; ++i) {
        const int u = i * 256 + t;
        if (u < 392) {
            const int pp = u >> 3, ch8 = (u & 7) * 8;
            const int py = pp / 7, px_ = pp - py * 7;
            const int base00 = (py * 2) * 14 + px_ * 2;
            s16x8 o;
            #pragma unroll
            for (int e = 0; e < 8; ++e) {
                const int c = ch8 + e;
                const float m0 = fmaxf(xT[(base00)      * 68 + c], xT[(base00 + 1)  * 68 + c]);
                const float m1 = fmaxf(xT[(base00 + 14) * 68 + c], xT[(base00 + 15) * 68 + c]);
                o[e] = (short)f2bf(fmaxf(m0, m1));
            }
            *(s16x8*)(xkv + ((size_t)b * NKEY + r * PP + pp) * CIN + g * 64 + ch8) = o;
        }
    }
}

// ============ fused Q/K/V MFMA GEMM. grid 588 x 128thr (2 waves), 64m x 128n.
// Q-blocks (bx<392): stage 64px x 256ch straight from rois into LDS
// (transpose + bf16, XOR-swizzled pitch 264). K/V: read xkv.
// Q/K operand-swapped (s16x4 stores); V natural order.
__global__ __launch_bounds__(128) void gemm_fused_kernel(
    const float* __restrict__ rois, const unsigned short* __restrict__ xkv,
    const unsigned short* __restrict__ wqb, const unsigned short* __restrict__ wkb,
    const unsigned short* __restrict__ wvb,
    const float* __restrict__ bq, const float* __restrict__ bk, const float* __restrict__ bv,
    unsigned short* __restrict__ q, unsigned short* __restrict__ kmat,
    unsigned short* __restrict__ vt_g)
{
    const int bx = blockIdx.x;
    const int t = threadIdx.x;
    const int wid = t >> 6, lane = t & 63;
    const int quad = lane >> 4, c = lane & 15;

    __shared__ unsigned short xT[64 * 264];   // Q staging tile (33.8 KB)

    f32x4 acc[4][4];
    #pragma unroll
    for (int i = 0; i < 4; ++i)
        #pragma unroll
        for (int j = 0; j < 4; ++j) acc[i][j] = (f32x4)(0.f);

    if (bx < 392) {
        // ---- Q: stage x-tile from rois (fp32 -> bf16 transpose in LDS)
        const int m0 = bx * 64;
        {
            const int c_loc = t >> 2;    // 0..31
            const int pq4   = t & 3;
            const int sw    = pq4 << 3;  // = ((row>>2)&3)<<3 for rows below
            #pragma unroll
            for (int ci = 0; ci < 8; ++ci) {
                const int ch = ci * 32 + c_loc;
                #pragma unroll
                for (int j = 0; j < 4; ++j) {
                    const int idx4 = (m0 >> 2) + pq4 + 4 * j;
                    const int n_img = idx4 / 49;
                    const int p4 = idx4 - n_img * 49;
                    const float4 v = ((const float4*)(rois + ((size_t)(n_img * CIN + ch)) * P))[p4];
                    const int r0 = (pq4 + 4 * j) * 4;
                    const int cs = ch ^ sw;
                    xT[(r0 + 0) * 264 + cs] = f2bf(v.x);
                    xT[(r0 + 1) * 264 + cs] = f2bf(v.y);
                    xT[(r0 + 2) * 264 + cs] = f2bf(v.z);
                    xT[(r0 + 3) * 264 + cs] = f2bf(v.w);
                }
            }
        }
        __syncthreads();

        const int m_base = m0;
        const int n_base = wid * 64;
        const int swr = ((c >> 2) & 3) << 3;   // read-side swizzle (row>>2)&3
        #pragma unroll
        for (int ks = 0; ks < 8; ++ks) {
            s16x8 af[4], bf[4];
            #pragma unroll
            for (int mt = 0; mt < 4; ++mt)
                af[mt] = *(const s16x8*)&xT[(mt * 16 + c) * 264 + ((ks * 32 + quad * 8) ^ swr)];
            #pragma unroll
            for (int nt = 0; nt < 4; ++nt)
                bf[nt] = *(const s16x8*)(wqb + (size_t)(n_base + nt * 16 + c) * CIN + ks * 32 + quad * 8);
            #pragma unroll
            for (int mt = 0; mt < 4; ++mt)
                #pragma unroll
                for (int nt = 0; nt < 4; ++nt)
                    acc[mt][nt] = __builtin_amdgcn_mfma_f32_16x16x32_bf16(bf[nt], af[mt], acc[mt][nt], 0, 0, 0);
        }
        #pragma unroll
        for (int mt = 0; mt < 4; ++mt) {
            const int m = m_base + mt * 16 + c;
            #pragma unroll
            for (int nt = 0; nt < 4; ++nt) {
                const int n0 = n_base + nt * 16 + quad * 4;
                const float4 b4 = *(const float4*)&bq[n0];
                s16x4 o4;
                o4[0] = (short)f2bf(acc[mt][nt][0] + b4.x);
                o4[1] = (short)f2bf(acc[mt][nt][1] + b4.y);
                o4[2] = (short)f2bf(acc[mt][nt][2] + b4.z);
                o4[3] = (short)f2bf(acc[mt][nt][3] + b4.w);
                *(s16x4*)(q + (size_t)m * HID + n0) = o4;
            }
        }
        return;
    }

    const unsigned short* w; const float* bias;
    int m_blk, mode;   // 1=K, 2=V
    if (bx < 490) { mode = 1; w = wkb; bias = bk; m_blk = bx - 392; }
    else          { mode = 2; w = wvb; bias = bv; m_blk = bx - 490; }
    const int m_base = m_blk * 64;
    const int n_base = wid * 64;

    if (mode == 1) {
        #pragma unroll
        for (int ks = 0; ks < 8; ++ks) {
            s16x8 af[4], bf[4];
            #pragma unroll
            for (int mt = 0; mt < 4; ++mt)
                af[mt] = *(const s16x8*)(xkv + (size_t)(m_base + mt * 16 + c) * CIN + ks * 32 + quad * 8);
            #pragma unroll
            for (int nt = 0; nt < 4; ++nt)
                bf[nt] = *(const s16x8*)(w + (size_t)(n_base + nt * 16 + c) * CIN + ks * 32 + quad * 8);
            #pragma unroll
            for (int mt = 0; mt < 4; ++mt)
                #pragma unroll
                for (int nt = 0; nt < 4; ++nt)
                    acc[mt][nt] = __builtin_amdgcn_mfma_f32_16x16x32_bf16(bf[nt], af[mt], acc[mt][nt], 0, 0, 0);
        }
        #pragma unroll
        for (int mt = 0; mt < 4; ++mt) {
            const int m = m_base + mt * 16 + c;
            #pragma unroll
            for (int nt = 0; nt < 4; ++nt) {
                const int n0 = n_base + nt * 16 + quad * 4;
                const float4 b4 = *(const float4*)&bias[n0];
                s16x4 o4;
                o4[0] = (short)f2bf(acc[mt][nt][0] + b4.x);
                o4[1] = (short)f2bf(acc[mt][nt][1] + b4.y);
                o4[2] = (short)f2bf(acc[mt][nt][2] + b4.z);
                o4[3] = (short)f2bf(acc[mt][nt][3] + b4.w);
                *(s16x4*)(kmat + (size_t)m * HID + n0) = o4;
            }
        }
    } else {
        #pragma unroll
        for (int ks = 0; ks < 8; ++ks) {
            s16x8 af[4], bf[4];
            #pragma unroll
            for (int mt = 0; mt < 4; ++mt)
                af[mt] = *(const s16x8*)(xkv + (size_t)(m_base + mt * 16 + c) * CIN + ks * 32 + quad * 8);
            #pragma unroll
            for (int nt = 0; nt < 4; ++nt)
                bf[nt] = *(const s16x8*)(w + (size_t)(n_base + nt * 16 + c) * CIN + ks * 32 + quad * 8);
            #pragma unroll
            for (int mt = 0; mt < 4; ++mt)
                #pragma unroll
                for (int nt = 0; nt < 4; ++nt)
                    acc[mt][nt] = __builtin_amdgcn_mfma_f32_16x16x32_bf16(af[mt], bf[nt], acc[mt][nt], 0, 0, 0);
        }
        #pragma unroll
        for (int nt = 0; nt < 4; ++nt) {
            const int d = n_base + nt * 16 + c;
            const float bv_ = bias[d];
            #pragma unroll
            for (int mt = 0; mt < 4; ++mt) {
                const int key0 = m_base + mt * 16 + quad * 4;
                const int bb = (key0 >= NKEY) ? 1 : 0;
                const int kl = key0 - bb * NKEY;
                s16x4 o4;
                #pragma unroll
                for (int rr = 0; rr < 4; ++rr)
                    o4[rr] = (short)f2bf(acc[mt][nt][rr] + bv_);
                *(s16x4*)(vt_g + ((size_t)bb * HID + d) * NKEY + kl) = o4;
            }
        }
    }
}

// ============ MFMA attention (FROZEN: round-8 structure + XCD remap; 64.5-68us).
__global__ __launch_bounds__(256, 2) void attn_kernel(
    const unsigned short* __restrict__ q, const unsigned short* __restrict__ kmat,
    const unsigned short* __restrict__ vt_g,
    unsigned short* __restrict__ opart, float* __restrict__ lpart)
{
    // ---- bijective XCD remap (m204): 490 blocks, 8 XCDs, q=61 r=2.
    const int fid  = blockIdx.x;
    const int xcd  = fid & 7, slot = fid >> 3;
    const int wg   = (xcd < 2 ? xcd * 62 : 124 + (xcd - 2) * 61) + slot;
    const int g    = wg / NS;          // q-group 0..97
    const int s    = wg - g * NS;      // split 0..4 (consecutive within XCD)
    const int qblk = g % 49;
    const int b    = g / 49;

    const int tid  = threadIdx.x;
    const int w    = tid >> 6;
    const int lane = tid & 63;
    const int quad = lane >> 4;
    const int c    = lane & 15;
    const int qb   = qblk * 256 + w * 64;

    __shared__ unsigned short Kst[2][32 * 128];   // [buf][key][d], row 256B, XOR-swz (16KB)
    __shared__ unsigned short Vst[2][128 * 32];   // [buf][d][key], row 64B, slot-XOR (16KB)
    __shared__ unsigned short Ps[4][64 * 72];     // wave-private P round-trip (36.9KB)

    const unsigned short* qg = q    + (size_t)b * NQ   * HID;
    const unsigned short* kg = kmat + (size_t)b * NKEY * HID;
    const unsigned short* vt = vt_g + (size_t)b * HID  * NKEY;

    int koff[2], voff[2];
    #pragma unroll
    for (int i = 0; i < 2; ++i) {
        const int dstk = w * 2048 + (i * 64 + lane) * 16;
        koff[i] = dstk ^ (((dstk >> 8) & 7) << 4);
        const int chunk = i * 64 + lane;
        const int d = w * 32 + (chunk >> 2), sl = chunk & 3;
        voff[i] = d * (NKEY * 2) + ((sl ^ (d & 3)) * 16);
    }
    const char* kc = (const char*)kg;
    const char* vc = (const char*)vt;

    // 98 key-tiles split NS=5 ways: {20,20,20,19,19}
    const int B6[6] = {0, 20, 40, 60, 79, 98};
    const int kt0 = B6[s], kt1 = B6[s + 1];

    // ---- prologue: stage first tile; load Q frags (overlaps)
    {
        const char* ks_ = kc + (size_t)kt0 * 8192;
        const char* vs_ = vc + (size_t)kt0 * 64;
        #pragma unroll
        for (int i = 0; i < 2; ++i) {
            __builtin_amdgcn_global_load_lds(GLOBAL_AS(ks_ + koff[i]),
                LDS_AS((char*)&Kst[0][0] + w * 2048 + i * 1024), 16, 0, 0);
            __builtin_amdgcn_global_load_lds(GLOBAL_AS(vs_ + voff[i]),
                LDS_AS((char*)&Vst[0][0] + w * 2048 + i * 1024), 16, 0, 0);
        }
    }

    s16x8 qf[4][4];
    #pragma unroll
    for (int nt = 0; nt < 4; ++nt)
        #pragma unroll
        for (int ks = 0; ks < 4; ++ks)
            qf[nt][ks] = *(const s16x8*)(qg + (size_t)(qb + nt * 16 + c) * HID + ks * 32 + quad * 8);

    f32x4 Ob[4][8];
    #pragma unroll
    for (int nt = 0; nt < 4; ++nt)
        #pragma unroll
        for (int nd = 0; nd < 8; ++nd) Ob[nt][nd] = (f32x4)(0.f);
    float l[4] = {0.f, 0.f, 0.f, 0.f};

    __syncthreads();    // drains vmcnt: tile kt0 staged

    int buf = 0;
    for (int kt = kt0; kt < kt1; ++kt) {
        if (kt + 1 < kt1) {
            const char* ks_ = kc + (size_t)(kt + 1) * 8192;
            const char* vs_ = vc + (size_t)(kt + 1) * 64;
            #pragma unroll
            for (int i = 0; i < 2; ++i) {
                __builtin_amdgcn_global_load_lds(GLOBAL_AS(ks_ + koff[i]),
                    LDS_AS((char*)&Kst[buf ^ 1][0] + w * 2048 + i * 1024), 16, 0, 0);
                __builtin_amdgcn_global_load_lds(GLOBAL_AS(vs_ + voff[i]),
                    LDS_AS((char*)&Vst[buf ^ 1][0] + w * 2048 + i * 1024), 16, 0, 0);
            }
        }

        const char* Kb = (const char*)&Kst[buf][0];
        const char* Vb = (const char*)&Vst[buf][0];

        // ---- S^T = K.Q^T : K frags from LDS (swizzled read)
        f32x4 st[2][4];
        #pragma unroll
        for (int mt = 0; mt < 2; ++mt)
            #pragma unroll
            for (int nt = 0; nt < 4; ++nt) st[mt][nt] = (f32x4)(0.f);
        #pragma unroll
        for (int mt = 0; mt < 2; ++mt) {
            const int row = mt * 16 + c;
            s16x8 kf[4];
            #pragma unroll
            for (int ks = 0; ks < 4; ++ks)
                kf[ks] = *(const s16x8*)(Kb + ((row * 256 + ks * 64 + quad * 16) ^ ((c & 7) << 4)));
            #pragma unroll
            for (int ks = 0; ks < 4; ++ks)
                #pragma unroll
                for (int nt = 0; nt < 4; ++nt)
                    st[mt][nt] = __builtin_amdgcn_mfma_f32_16x16x32_bf16(kf[ks], qf[nt][ks], st[mt][nt], 0, 0, 0);
        }

        // ---- exp (no max: scores bounded, fp32-safe), pack -> Ps[q][key]
        #pragma unroll
        for (int mt = 0; mt < 2; ++mt) {
            #pragma unroll
            for (int nt = 0; nt < 4; ++nt) {
                const float e0 = __expf(st[mt][nt][0]);
                const float e1 = __expf(st[mt][nt][1]);
                const float e2 = __expf(st[mt][nt][2]);
                const float e3 = __expf(st[mt][nt][3]);
                l[nt] += (e0 + e1) + (e2 + e3);
                u32x2 pk;
                pk[0] = (unsigned int)f2bf(e0) | ((unsigned int)f2bf(e1) << 16);
                pk[1] = (unsigned int)f2bf(e2) | ((unsigned int)f2bf(e3) << 16);
                *(u32x2*)&Ps[w][(nt * 16 + c) * 72 + mt * 16 + quad * 4] = pk;
            }
        }
        // wave-private P: intra-wave DS ordering suffices.

        // ---- O += P.V : A=P from LDS, B=Vt from LDS (slot-XOR read)
        s16x8 pf[4];
        #pragma unroll
        for (int nt = 0; nt < 4; ++nt)
            pf[nt] = *(const s16x8*)&Ps[w][(nt * 16 + c) * 72 + quad * 8];
        #pragma unroll
        for (int g2 = 0; g2 < 2; ++g2) {
            s16x8 vf[4];
            #pragma unroll
            for (int dd = 0; dd < 4; ++dd) {
                const int d = (g2 * 4 + dd) * 16 + c;
                vf[dd] = *(const s16x8*)(Vb + (d * 64 + ((quad ^ (d & 3)) * 16)));
            }
            #pragma unroll
            for (int dd = 0; dd < 4; ++dd)
                #pragma unroll
                for (int nt = 0; nt < 4; ++nt)
                    Ob[nt][g2 * 4 + dd] = __builtin_amdgcn_mfma_f32_16x16x32_bf16(pf[nt], vf[dd], Ob[nt][g2 * 4 + dd], 0, 0, 0);
        }

        if (kt + 1 < kt1) __syncthreads();
        buf ^= 1;
    }

    // epilogue: bf16 unnormalized partials
    unsigned short* Op = opart + (size_t)(s * 2 + b) * NQ * HID;
    #pragma unroll
    for (int nt = 0; nt < 4; ++nt) {
        #pragma unroll
        for (int nd = 0; nd < 8; ++nd) {
            #pragma unroll
            for (int rr = 0; rr < 4; ++rr) {
                const int qrow = qb + nt * 16 + quad * 4 + rr;
                Op[(size_t)qrow * HID + nd * 16 + c] = f2bf(Ob[nt][nd][rr]);
            }
        }
    }
    #pragma unroll
    for (int nt = 0; nt < 4; ++nt) {
        l[nt] += __shfl_xor(l[nt], 16, 64);
        l[nt] += __shfl_xor(l[nt], 32, 64);
    }
    if (quad == 0) {
        float* lp = lpart + (size_t)(s * 2 + b) * NQ;
        #pragma unroll
        for (int nt = 0; nt < 4; ++nt) lp[qb + nt * 16 + c] = l[nt];
    }
}

// ============ outproj: merge NS bf16 slices + normalize, then out = rois + wre@y + bre
// grid 392, 256 thr = 4 waves; block tile 256o x 64m. Swapped MFMA + float4 epilogue.
__global__ __launch_bounds__(256) void outproj_kernel(
    const float* __restrict__ rois,
    const unsigned short* __restrict__ opart, const float* __restrict__ lpart,
    const unsigned short* __restrict__ wreb, const float* __restrict__ bre,
    float* __restrict__ out)
{
    const int t = threadIdx.x;
    const int wid = t >> 6, lane = t & 63;
    const int quad = lane >> 4, c = lane & 15;
    const int m0 = blockIdx.x * 64;                 // global m in [0, 25088)
    const int b  = (m0 >= NQ) ? 1 : 0;

    __shared__ unsigned short ys[64 * 136];         // merged y tile bf16 [m][k]

    {
        const int m_loc = t >> 2, kq = t & 3;
        const int q_local = (m0 + m_loc) - b * NQ;
        float lsum = 0.f;
        #pragma unroll
        for (int sl = 0; sl < NS; ++sl)
            lsum += lpart[(size_t)(sl * 2 + b) * NQ + q_local];
        const float invl = 1.0f / lsum;
        #pragma unroll
        for (int ch = 0; ch < 4; ++ch) {
            float a8[8] = {0, 0, 0, 0, 0, 0, 0, 0};
            #pragma unroll
            for (int sl = 0; sl < NS; ++sl) {
                const s16x8 v = *(const s16x8*)&opart[
                    ((size_t)(sl * 2 + b) * NQ + q_local) * HID + kq * 32 + ch * 8];
                #pragma unroll
                for (int e = 0; e < 8; ++e) a8[e] += bf2f((unsigned short)v[e]);
            }
            s16x8 o;
            #pragma unroll
            for (int e = 0; e < 8; ++e) o[e] = (short)f2bf(a8[e] * invl);
            *(s16x8*)&ys[m_loc * 136 + kq * 32 + ch * 8] = o;
        }
    }
    __syncthreads();

    // wre frags: B-operand rows = o (this wave's 64 outputs)
    const int o_base = wid * 64;
    s16x8 wf[4][4];
    #pragma unroll
    for (int ot = 0; ot < 4; ++ot)
        #pragma unroll
        for (int ks = 0; ks < 4; ++ks)
            wf[ot][ks] = *(const s16x8*)(wreb + (size_t)(o_base + ot * 16 + c) * HID + ks * 32 + quad * 8);

    f32x4 acc[4][4];   // [mt][ot]: row=m (quad*4+rr), col=o (c)
    #pragma unroll
    for (int i = 0; i < 4; ++i)
        #pragma unroll
        for (int j = 0; j < 4; ++j) acc[i][j] = (f32x4)(0.f);

    #pragma unroll
    for (int ks = 0; ks < 4; ++ks) {
        s16x8 yf[4];
        #pragma unroll
        for (int mt = 0; mt < 4; ++mt)
            yf[mt] = *(const s16x8*)&ys[(mt * 16 + c) * 136 + ks * 32 + quad * 8];
        #pragma unroll
        for (int mt = 0; mt < 4; ++mt)
            #pragma unroll
            for (int ot = 0; ot < 4; ++ot)
                acc[mt][ot] = __builtin_amdgcn_mfma_f32_16x16x32_bf16(yf[mt], wf[ot][ks], acc[mt][ot], 0, 0, 0);
    }

    // ---- epilogue: out[n][o][p..p+3] = rois + bre[o] + T — float4 per (mt,ot)
    #pragma unroll
    for (int ot = 0; ot < 4; ++ot) {
        const int o = o_base + ot * 16 + c;
        const float br = bre[o];
        #pragma unroll
        for (int mt = 0; mt < 4; ++mt) {
            const int m_g = m0 + mt * 16 + quad * 4;     // +rr consecutive (p-contig)
            const int mm  = m_g - b * NQ;
            const int r_roi = mm / 196;
            const int p     = mm - r_roi * 196;
            const int n_img = b * 64 + r_roi;
            const size_t base = ((size_t)n_img * CIN + o) * P + p;
            const float4 rv = *(const float4*)&rois[base];
            float4 ov;
            ov.x = rv.x + br + acc[mt][ot][0];
            ov.y = rv.y + br + acc[mt][ot][1];
            ov.z = rv.z + br + acc[mt][ot][2];
            ov.w = rv.w + br + acc[mt][ot][3];
            *(float4*)&out[base] = ov;
        }
    }
}

extern "C" void kernel_launch(void* const* d_in, const int* in_sizes, int n_in,
                              void* d_out, int out_size, void* d_ws, size_t ws_size,
                              hipStream_t stream)
{
    (void)in_sizes; (void)n_in; (void)out_size; (void)ws_size;
    const float* rois = (const float*)d_in[0];
    const float* wq  = (const float*)d_in[2];
    const float* bq  = (const float*)d_in[3];
    const float* wk  = (const float*)d_in[4];
    const float* bk  = (const float*)d_in[5];
    const float* wv  = (const float*)d_in[6];
    const float* bv  = (const float*)d_in[7];
    const float* wre = (const float*)d_in[8];
    const float* bre = (const float*)d_in[9];
    float* out = (float*)d_out;

    char* ws = (char*)d_ws;
    // opart: 10 slices (NS=5 x 2 batches) x NQ x HID bf16 = 32,112,640 B at 0.
    // Aliases ONLY buffers fully consumed by gemm_fused before attn runs:
    //   xkv [12,845,056, 16,056,320),  wqb/wkb/wvb [16,056,320, 16,252,928).
    unsigned short* opart = (unsigned short*)(ws);
    unsigned short* xkv   = (unsigned short*)(ws + 12845056);
    unsigned short* wqb   = (unsigned short*)(ws + 16056320);   //  65,536
    unsigned short* wkb   = (unsigned short*)(ws + 16121856);   //  65,536
    unsigned short* wvb   = (unsigned short*)(ws + 16187392);   //  65,536
    // survivors live past opart (32,112,640):
    unsigned short* q     = (unsigned short*)(ws + 32112640);   // 6,422,528
    unsigned short* kmat  = (unsigned short*)(ws + 38535168);   // 1,605,632
    unsigned short* vt_g  = (unsigned short*)(ws + 40140800);   // 1,605,632
    float*          lpart = (float*)         (ws + 41746432);   //   501,760
    unsigned short* wreb  = (unsigned short*)(ws + 42248192);   //    65,536
    // total: 42,313,728 B

    prep_kernel<<<dim3(516), 256, 0, stream>>>(rois, wq, wk, wv, wre,
                                               xkv, wqb, wkb, wvb, wreb);
    gemm_fused_kernel<<<dim3(588), 128, 0, stream>>>(rois, xkv, wqb, wkb, wvb,
                                                     bq, bk, bv, q, kmat, vt_g);
    attn_kernel<<<dim3(490), 256, 0, stream>>>(q, kmat, vt_g, opart, lpart);
    outproj_kernel<<<dim3(392), 256, 0, stream>>>(rois, opart, lpart, wreb, bre, out);
}